// Round 8
// baseline (264.980 us; speedup 1.0000x reference)
//
#include <hip/hip_runtime.h>
#include <stdint.h>
#include <math.h>

#define DEV static __device__ __forceinline__

typedef __attribute__((ext_vector_type(8))) __bf16 bf16x8;
typedef __attribute__((ext_vector_type(4))) float f32x4;
typedef unsigned short u16;

// fp32 -> bf16, round-to-nearest-even
DEV u16 f2b(float f) {
  union { float f; uint32_t u; } x; x.f = f;
  uint32_t r = x.u + 0x7fffu + ((x.u >> 16) & 1u);
  return (u16)(r >> 16);
}

DEV uint32_t pk2(float a, float b) {
  return (uint32_t)f2b(a) | ((uint32_t)f2b(b) << 16);
}

DEV float b2f_lo(uint32_t u) { return __uint_as_float(u << 16); }
DEV float b2f_hi(uint32_t u) { return __uint_as_float(u & 0xffff0000u); }

DEV void glds16(const void* g, void* l) {
  __builtin_amdgcn_global_load_lds(
      (const __attribute__((address_space(1))) void*)g,
      (__attribute__((address_space(3))) void*)l, 16, 0, 0);
}

DEV f32x4 mfma16(bf16x8 a, bf16x8 b, f32x4 c) {
  return __builtin_amdgcn_mfma_f32_16x16x32_bf16(a, b, c, 0, 0, 0);
}

#define BAR() __builtin_amdgcn_s_barrier()
#define WAIT_LGKM()                                      \
  {                                                      \
    asm volatile("s_waitcnt lgkmcnt(0)" ::: "memory");   \
    __builtin_amdgcn_sched_barrier(0);                   \
  }
#define WAIT_VM4() asm volatile("s_waitcnt vmcnt(4)" ::: "memory")
#define WAIT_VM0() asm volatile("s_waitcnt vmcnt(0)" ::: "memory")

// ---------------- single fused fp32 -> bf16 conversion ----------------
__global__ __launch_bounds__(256) void cvt_all(
    const float* __restrict__ x, const float* __restrict__ Wq,
    const float* __restrict__ Wk, const float* __restrict__ Wv,
    const float* __restrict__ Wo, const float* __restrict__ bias,
    u16* __restrict__ xb, u16* __restrict__ wqkv, u16* __restrict__ wo,
    u16* __restrict__ biasb) {
  size_t i = ((size_t)blockIdx.x * 256 + threadIdx.x) * 4;
  const float* s;
  u16* d;
  size_t off;
  float scale = 1.0f;
  if (i < 8388608)        { s = x;  d = xb;             off = i; }
  else if (i < 9437184)   { s = Wq; d = wqkv;           off = i - 8388608; }
  else if (i < 10485760)  { s = Wk; d = wqkv + 1048576; off = i - 9437184; }
  else if (i < 11534336)  { s = Wv; d = wqkv + 2097152; off = i - 10485760; }
  else if (i < 12582912)  { s = Wo; d = wo;             off = i - 11534336; }
  else { s = bias; d = biasb; off = i - 12582912; scale = 1.44269504f; }
  float4 v = *(const float4*)(s + off);
  ushort4 o;
  o.x = f2b(v.x * scale); o.y = f2b(v.y * scale);
  o.z = f2b(v.z * scale); o.w = f2b(v.w * scale);
  *(ushort4*)(d + off) = o;
}

// ========= shared ring-3 GEMM core (BM=128,BN=128, 4 waves, 48 KiB) =======
// 256 threads = 4 waves (wm=wave>>1 over 128 rows, wn=wave&1 over 128 cols),
// per-wave output 64x64 (4x4 frags). K in 32-wide halves g=0..31. LDS ring of
// THREE 8 KiB regions per operand (48 KiB total -> 3 blocks/CU = 12 waves/CU;
// round-7's 72 KiB 8-wave version only fit 2 blocks/CU and left a lone-tile
// tail: 768 tiles over 512 slots). Phase g: read slot g%3 (8 ds_read_b128),
// stage K-half g+2 into slot (g+2)%3 (4 glds16/wave), BAR, lgkm0, 16 MFMA,
// vmcnt(4) draining the PREVIOUS phase's stages = the K-half read next phase.
// Loads never drain to 0 mid-loop. XOR k-colgroup swizzle (0 bank conflicts).

DEV void stage_slot(const u16* A, const u16* Bw, int m0, int n0, int col,
                    int wave, int srow, int scol, u16* slotA, u16* slotB) {
#pragma unroll
  for (int cc = 0; cc < 2; ++cc) {
    int unit = wave * 2 + cc;
    int r = unit * 16 + srow;
    glds16(A + (size_t)(m0 + r) * 1024 + col + scol, slotA + unit * 512);
    glds16(Bw + (size_t)(n0 + r) * 1024 + col + scol, slotB + unit * 512);
  }
}

DEV void load_frags(const u16* Rbase, const u16* Cbase, int wr, int wc,
                    int c16, int swz, bf16x8 rf[4], bf16x8 cf[4]) {
#pragma unroll
  for (int i = 0; i < 4; ++i)
    rf[i] = *(const bf16x8*)&Rbase[(wr * 64 + i * 16 + c16) * 32 + swz];
#pragma unroll
  for (int i = 0; i < 4; ++i)
    cf[i] = *(const bf16x8*)&Cbase[(wc * 64 + i * 16 + c16) * 32 + swz];
}

DEV void mfma_all(bf16x8 rf[4], bf16x8 cf[4], f32x4 acc[4][4]) {
#pragma unroll
  for (int i = 0; i < 4; ++i)
#pragma unroll
    for (int j = 0; j < 4; ++j) acc[i][j] = mfma16(rf[i], cf[j], acc[i][j]);
}

DEV void gemm_core(const u16* A, const u16* Bw, int m0, int n0, bool vblk,
                   int wave, int lane, u16 (*lsA)[4096], u16 (*lsB)[4096],
                   f32x4 acc[4][4]) {
  int q16 = lane >> 4, c16 = lane & 15;
  int wm = wave >> 1, wn = wave & 1;
  int wr = vblk ? wn : wm, wc = vblk ? wm : wn;
  int srow = lane >> 2;
  int scol = ((lane & 3) ^ ((lane >> 3) & 3)) * 8;  // staged XOR colgroup
  int swz = (q16 ^ ((c16 >> 1) & 3)) * 8;           // read-side colgroup

  // prologue: stage K-halves 0,1 (8 loads); drain half 0, keep 4 in flight
  stage_slot(A, Bw, m0, n0, 0, wave, srow, scol, lsA[0], lsB[0]);
  stage_slot(A, Bw, m0, n0, 32, wave, srow, scol, lsA[1], lsB[1]);
  WAIT_VM4();
  BAR();

#pragma unroll
  for (int g = 0; g < 32; ++g) {
    const int slot = g % 3;
    const u16* Rb = vblk ? &lsB[slot][0] : &lsA[slot][0];
    const u16* Cb = vblk ? &lsA[slot][0] : &lsB[slot][0];
    bf16x8 rf[4], cf[4];
    load_frags(Rb, Cb, wr, wc, c16, swz, rf, cf);
    if (g < 30)
      stage_slot(A, Bw, m0, n0, (g + 2) * 32, wave, srow, scol,
                 lsA[(g + 2) % 3], lsB[(g + 2) % 3]);
    BAR();
    WAIT_LGKM();
    __builtin_amdgcn_s_setprio(1);
    mfma_all(rf, cf, acc);
    __builtin_amdgcn_s_setprio(0);
    if (g < 30) { WAIT_VM4(); } else if (g == 30) { WAIT_VM0(); }
    BAR();
  }
}

// ---------------- fused QKV projection GEMM ----------------
// A: (8192,1024) bf16 (x). Bw: (3072,1024) bf16 = [Wq;Wk;Wv] rows.
// Q,K -> (BH, T, 72) padded;  V -> (BH, 4, 64, 136) pre-tiled V^T.
// Grid 24x64 = 1536 blocks = exactly 2 uniform rounds at 3 blocks/CU.
__global__ __launch_bounds__(256, 3) void gemm_qkv(
    const u16* __restrict__ A, const u16* __restrict__ Bw,
    const float* __restrict__ bq, const float* __restrict__ bk,
    const float* __restrict__ bv,
    u16* __restrict__ qo, u16* __restrict__ ko, u16* __restrict__ vto) {
  __shared__ u16 lsA[3][4096];  // 24 KiB
  __shared__ u16 lsB[3][4096];  // 24 KiB
  int tid = threadIdx.x, wave = tid >> 6, lane = tid & 63;
  int q16 = lane >> 4, c16 = lane & 15;
  int m0 = blockIdx.y * 128, n0 = blockIdx.x * 128;
  int wm = wave >> 1, wn = wave & 1;
  const bool vblk = (n0 >= 2048);

  f32x4 acc[4][4];
#pragma unroll
  for (int i = 0; i < 4; ++i)
#pragma unroll
    for (int j = 0; j < 4; ++j) acc[i][j] = (f32x4)0.0f;

  gemm_core(A, Bw, m0, n0, vblk, wave, lane, lsA, lsB, acc);

  if (!vblk) {
    // rows = m (t), cols = n (head dim)
#pragma unroll
    for (int mt = 0; mt < 4; ++mt) {
#pragma unroll
      for (int nt = 0; nt < 4; ++nt) {
        int n = n0 + wn * 64 + nt * 16 + c16;
        int which = n >> 10;
        int nl = n & 1023;
        int hh = nl >> 6, d = nl & 63;
        float bias = (which == 0 ? bq : bk)[nl];
        u16* dst = (which == 0 ? qo : ko);
#pragma unroll
        for (int r = 0; r < 4; ++r) {
          int m = m0 + wm * 64 + mt * 16 + q16 * 4 + r;
          int b = m >> 9, t = m & 511;
          size_t bh = (size_t)b * 16 + hh;
          dst[(bh * 512 + t) * 72 + d] = f2b(acc[mt][nt][r] + bias);
        }
      }
    }
  } else {
    // rows = n (head dim d), cols = m (t): D^T, coalesced over t
#pragma unroll
    for (int it = 0; it < 4; ++it) {
      int nbase = n0 + wn * 64 + it * 16 + q16 * 4;  // wr == wn
      float4 bvv = *(const float4*)(bv + (nbase & 1023));
#pragma unroll
      for (int jt = 0; jt < 4; ++jt) {
        int m = m0 + wm * 64 + jt * 16 + c16;  // wc == wm
        int b = m >> 9, t = m & 511;
        size_t bh4 = ((size_t)b * 16) * 4;
#pragma unroll
        for (int r = 0; r < 4; ++r) {
          int nl = (nbase + r) & 1023;
          int hh = nl >> 6, d = nl & 63;
          float bias = ((const float*)&bvv)[r];
          vto[((bh4 + (size_t)hh * 4 + (t >> 7)) * 64 + d) * 136 + (t & 127)] =
              f2b(acc[it][jt][r] + bias);
        }
      }
    }
  }
}

// ---------------- flash attention (S^T orientation) ----------------
// q,k: (BH, 512, 72) bf16 padded; vt: (BH, 4, 64, 136) bf16 pre-tiled V^T
// biasb: (H,512,512) bf16, pre-scaled by log2(e). out: (B,T,C) bf16.
// Work-balanced 640-block grid (4 tile-iters per block), 4 waves x 32 q-rows.
// LDS = 18432(K) + 17408(V) + 17408(P, stride 68) = 53248 B = 52.0 KiB ->
// 3 blocks/CU. 640 blocks <= 768 slots -> fully resident from t=0.
// NOTE round-5 lesson: do NOT cap VGPRs below live state (launch_bounds
// (512,6) forced 40 VGPR -> ~200 MB scratch spill traffic, 117 us).
__global__ __launch_bounds__(256, 3) void attn_kernel(
    const u16* __restrict__ qglob, const u16* __restrict__ kglob,
    const u16* __restrict__ vtglob, const u16* __restrict__ biasb,
    u16* __restrict__ og) {
  __shared__ u16 lsK[128 * 72];      // K tile (s,d) padded; also Q staging
  __shared__ u16 lsV[64 * 136];      // V^T tile (d,s) padded
  __shared__ u16 lsP[4 * 32 * 68];   // per-wave P half-tile (q, s-half)

  int tid = threadIdx.x, wave = tid >> 6, lane = tid & 63;
  int q16 = lane >> 4, c16 = lane & 15;
  u16* lsPw = lsP + wave * (32 * 68);

  int p = blockIdx.x;
  int bx, bh, bx2 = -1, bh2 = 0;
  if (p < 256)      { bx = 3; bh = p; }
  else if (p < 512) { bx = 2; bh = p - 256; bx2 = 0; bh2 = p - 256; }
  else              { int q = p - 512; bx = 1; bh = 2 * q; bx2 = 1; bh2 = 2 * q + 1; }

  for (;;) {
    int b = bh >> 4, h = bh & 15;
    int q0 = bx * 128;

    const u16* qbase = qglob + (size_t)bh * (512 * 72) + (size_t)q0 * 72;
    const u16* kbase = kglob + (size_t)bh * (512 * 72);
    const u16* vbase = vtglob + (size_t)bh * 4 * (64 * 136);

    // stage Q tile (contiguous 128x72 u16) into lsK
    for (int i = wave; i < 18; i += 4)
      glds16(qbase + (size_t)i * 512 + lane * 8, lsK + i * 512);
    __syncthreads();
    bf16x8 qf[2][2];
#pragma unroll
    for (int nt = 0; nt < 2; ++nt)
#pragma unroll
      for (int ks = 0; ks < 2; ++ks)
        qf[nt][ks] = *(const bf16x8*)&lsK[(wave * 32 + nt * 16 + c16) * 72 +
                                          ks * 32 + q16 * 8];

    f32x4 oacc[2][4];
#pragma unroll
    for (int i = 0; i < 2; ++i)
#pragma unroll
      for (int j = 0; j < 4; ++j) oacc[i][j] = (f32x4)0.0f;
    float mold[2] = {-INFINITY, -INFINITY};
    float lsum[2] = {0.0f, 0.0f};
    const float SCL = 0.18033688f;  // (1/sqrt(64)) * log2(e)

    for (int st = 0; st <= bx; ++st) {
      bool diag = (st == bx);
      __syncthreads();  // prior iter done with lsK/lsV/lsP
      const u16* kt = kbase + (size_t)st * (128 * 72);
      for (int i = wave; i < 18; i += 4)
        glds16(kt + (size_t)i * 512 + lane * 8, lsK + i * 512);
      const u16* vt = vbase + (size_t)st * (64 * 136);
      for (int i = wave; i < 17; i += 4)
        glds16(vt + (size_t)i * 512 + lane * 8, lsV + i * 512);

      // prefetch bias rows (bf16, pre-scaled); completes during staging drain
      uint2 ub[2][8];
#pragma unroll
      for (int nt = 0; nt < 2; ++nt) {
        int qgl = q0 + wave * 32 + nt * 16 + c16;
        const u16* bp =
            biasb + ((size_t)h * 512 + qgl) * 512 + st * 128 + q16 * 4;
#pragma unroll
        for (int mt = 0; mt < 8; ++mt) ub[nt][mt] = *(const uint2*)(bp + mt * 16);
      }
      __syncthreads();  // drains vmcnt (staging + bias prefetch)

      // S^T = K Q^T : rows s (8 m-tiles), cols q (2 n-tiles = wave's 32 rows)
      f32x4 sa[8][2];
#pragma unroll
      for (int mt = 0; mt < 8; ++mt) {
        sa[mt][0] = (f32x4)0.0f;
        sa[mt][1] = (f32x4)0.0f;
      }
      int mtmax = diag ? 2 * wave + 2 : 8;
#pragma unroll
      for (int mt = 0; mt < 8; ++mt) {
        if (mt < mtmax) {
#pragma unroll
          for (int ks = 0; ks < 2; ++ks) {
            bf16x8 kf =
                *(const bf16x8*)&lsK[(mt * 16 + c16) * 72 + ks * 32 + q16 * 8];
            sa[mt][0] = mfma16(kf, qf[0][ks], sa[mt][0]);
            sa[mt][1] = mfma16(kf, qf[1][ks], sa[mt][1]);
          }
        }
      }

      // online softmax: reduce over s = (mt, r) in-register + 2 shuffles
      float alpha[2];
#pragma unroll
      for (int nt = 0; nt < 2; ++nt) {
#pragma unroll
        for (int mt = 0; mt < 8; ++mt) {
          uint32_t lo = ub[nt][mt].x, hi = ub[nt][mt].y;
          f32x4 bv;
          bv[0] = b2f_lo(lo); bv[1] = b2f_hi(lo);
          bv[2] = b2f_lo(hi); bv[3] = b2f_hi(hi);
          sa[mt][nt] = sa[mt][nt] * SCL + bv;
        }
        if (diag) {
          // mask s > q  (s0 == q0 on diagonal tile)
#pragma unroll
          for (int mt = 0; mt < 8; ++mt) {
            int d0 = mt * 16 + q16 * 4 - wave * 32 - nt * 16 - c16;
#pragma unroll
            for (int r = 0; r < 4; ++r)
              if (d0 + r > 0) sa[mt][nt][r] = -INFINITY;
          }
        }
        f32x4 m4 = sa[0][nt];
#pragma unroll
        for (int mt = 1; mt < 8; ++mt) {
          f32x4 v = sa[mt][nt];
          m4[0] = fmaxf(m4[0], v[0]); m4[1] = fmaxf(m4[1], v[1]);
          m4[2] = fmaxf(m4[2], v[2]); m4[3] = fmaxf(m4[3], v[3]);
        }
        float mx = fmaxf(fmaxf(m4[0], m4[1]), fmaxf(m4[2], m4[3]));
        mx = fmaxf(mx, __shfl_xor(mx, 16));
        mx = fmaxf(mx, __shfl_xor(mx, 32));
        float mnew = fmaxf(mold[nt], mx);
        alpha[nt] = exp2f(mold[nt] - mnew);
        mold[nt] = mnew;
        f32x4 s4 = (f32x4)0.0f;
#pragma unroll
        for (int mt = 0; mt < 8; ++mt) {
          f32x4 pq;
          pq[0] = exp2f(sa[mt][nt][0] - mnew);
          pq[1] = exp2f(sa[mt][nt][1] - mnew);
          pq[2] = exp2f(sa[mt][nt][2] - mnew);
          pq[3] = exp2f(sa[mt][nt][3] - mnew);
          sa[mt][nt] = pq;
          s4 += pq;
        }
        float ss = (s4[0] + s4[1]) + (s4[2] + s4[3]);
        ss += __shfl_xor(ss, 16);
        ss += __shfl_xor(ss, 32);
        lsum[nt] = lsum[nt] * alpha[nt] + ss;
      }

      // rescale O by alpha (broadcast col-state -> row-state via shfl)
#pragma unroll
      for (int mo = 0; mo < 2; ++mo) {
        f32x4 av;
#pragma unroll
        for (int r = 0; r < 4; ++r) av[r] = __shfl(alpha[mo], q16 * 4 + r);
#pragma unroll
        for (int dt = 0; dt < 4; ++dt) oacc[mo][dt] *= av;
      }

      // O += P V, in two s-halves through per-wave LDS (C-layout -> A-layout)
      int G = diag ? wave + 1 : 4;  // valid 32-wide s-groups
#pragma unroll
      for (int hf = 0; hf < 2; ++hf) {
        if (hf * 2 < G) {
#pragma unroll
          for (int nt = 0; nt < 2; ++nt)
#pragma unroll
            for (int mt4 = 0; mt4 < 4; ++mt4) {
              f32x4 pv = sa[hf * 4 + mt4][nt];
              uint2 w;
              w.x = pk2(pv[0], pv[1]);
              w.y = pk2(pv[2], pv[3]);
              *(uint2*)&lsPw[(nt * 16 + c16) * 68 + mt4 * 16 + q16 * 4] = w;
            }
#pragma unroll
          for (int ksh = 0; ksh < 2; ++ksh) {
            if (hf * 2 + ksh < G) {
              bf16x8 pf0 =
                  *(const bf16x8*)&lsPw[c16 * 68 + ksh * 32 + q16 * 8];
              bf16x8 pf1 =
                  *(const bf16x8*)&lsPw[(16 + c16) * 68 + ksh * 32 + q16 * 8];
#pragma unroll
              for (int dt = 0; dt < 4; ++dt) {
                bf16x8 vf = *(const bf16x8*)&lsV[(dt * 16 + c16) * 136 +
                                                 hf * 64 + ksh * 32 + q16 * 8];
                oacc[0][dt] = mfma16(pf0, vf, oacc[0][dt]);
                oacc[1][dt] = mfma16(pf1, vf, oacc[1][dt]);
              }
            }
          }
        }
      }
    }

    // epilogue: O /= l, write (B,T,C) bf16
#pragma unroll
    for (int mo = 0; mo < 2; ++mo) {
      f32x4 lv;
#pragma unroll
      for (int r = 0; r < 4; ++r) lv[r] = __shfl(lsum[mo], q16 * 4 + r);
#pragma unroll
      for (int r = 0; r < 4; ++r) {
        int tg = q0 + wave * 32 + mo * 16 + q16 * 4 + r;
        float inv = 1.0f / lv[r];
#pragma unroll
        for (int dt = 0; dt < 4; ++dt)
          og[((size_t)b * 512 + tg) * 1024 + h * 64 + dt * 16 + c16] =
              f2b(oacc[mo][dt][r] * inv);
      }
    }

    if (bx2 < 0) break;
    __syncthreads();  // job 2 re-stages Q into lsK; job 1 may still read LDS
    bx = bx2; bh = bh2; bx2 = -1;
  }
}

// ------------- output projection GEMM (same 128x128 ring-3 core) -----------
// Grid 8x64 = 512 blocks -> all resident (2/CU), uniform, no lockstep tail.
__global__ __launch_bounds__(256, 3) void gemm_out(
    const u16* __restrict__ A, const u16* __restrict__ W,
    const float* __restrict__ bo, float* __restrict__ out) {
  __shared__ u16 lsA[3][4096];  // 24 KiB
  __shared__ u16 lsB[3][4096];  // 24 KiB
  int tid = threadIdx.x, wave = tid >> 6, lane = tid & 63;
  int q16 = lane >> 4, c16 = lane & 15;
  int m0 = blockIdx.y * 128, n0 = blockIdx.x * 128;
  int wm = wave >> 1, wn = wave & 1;

  f32x4 acc[4][4];
#pragma unroll
  for (int i = 0; i < 4; ++i)
#pragma unroll
    for (int j = 0; j < 4; ++j) acc[i][j] = (f32x4)0.0f;

  gemm_core(A, W, m0, n0, false, wave, lane, lsA, lsB, acc);

#pragma unroll
  for (int mt = 0; mt < 4; ++mt) {
#pragma unroll
    for (int nt = 0; nt < 4; ++nt) {
      int n = n0 + wn * 64 + nt * 16 + c16;
      float bias = bo[n];
#pragma unroll
      for (int r = 0; r < 4; ++r) {
        int m = m0 + wm * 64 + mt * 16 + q16 * 4 + r;
        out[(size_t)m * 1024 + n] = acc[mt][nt][r] + bias;
      }
    }
  }
}

extern "C" void kernel_launch(void* const* d_in, const int* in_sizes, int n_in,
                              void* d_out, int out_size, void* d_ws, size_t ws_size,
                              hipStream_t stream) {
  const float* x    = (const float*)d_in[0];
  const float* Wq   = (const float*)d_in[1];
  const float* bq   = (const float*)d_in[2];
  const float* Wk   = (const float*)d_in[3];
  const float* bk   = (const float*)d_in[4];
  const float* Wv   = (const float*)d_in[5];
  const float* bv   = (const float*)d_in[6];
  const float* Wo   = (const float*)d_in[7];
  const float* bo   = (const float*)d_in[8];
  const float* bias = (const float*)d_in[9];
  float* out = (float*)d_out;

  const size_t MB = 1u << 20;
  char* ws = (char*)d_ws;
  u16* xb    = (u16*)(ws);              // 16 MiB: x bf16 / reused as attn out
  u16* wqkv  = (u16*)(ws + 16 * MB);    // 6 MiB
  u16* wo    = (u16*)(ws + 22 * MB);    // 2 MiB
  u16* biasb = (u16*)(ws + 24 * MB);    // 8 MiB (bf16, pre-scaled by log2e)
  u16* qb    = (u16*)(ws + 32 * MB);    // 18 MiB (BH,512,72)
  u16* kb    = (u16*)(ws + 50 * MB);    // 18 MiB (BH,512,72)
  u16* vtb   = (u16*)(ws + 68 * MB);    // 17 MiB (BH,4,64,136)
  u16* ab    = xb;                      // attn output overlays xb

  cvt_all<<<16384, 256, 0, stream>>>(x, Wq, Wk, Wv, Wo, bias,
                                     xb, wqkv, wo, biasb);
  gemm_qkv<<<dim3(24, 64), 256, 0, stream>>>(xb, wqkv, bq, bk, bv, qb, kb, vtb);
  attn_kernel<<<dim3(640), 256, 0, stream>>>(qb, kb, vtb, biasb, ab);
  gemm_out<<<dim3(8, 64), 256, 0, stream>>>(ab, wo, bo, out);
}

// Round 9
// 262.443 us; speedup vs baseline: 1.0097x; 1.0097x over previous
//
#include <hip/hip_runtime.h>
#include <stdint.h>
#include <math.h>

#define DEV static __device__ __forceinline__

typedef __attribute__((ext_vector_type(8))) __bf16 bf16x8;
typedef __attribute__((ext_vector_type(4))) float f32x4;
typedef unsigned short u16;

// fp32 -> bf16, round-to-nearest-even
DEV u16 f2b(float f) {
  union { float f; uint32_t u; } x; x.f = f;
  uint32_t r = x.u + 0x7fffu + ((x.u >> 16) & 1u);
  return (u16)(r >> 16);
}

DEV uint32_t pk2(float a, float b) {
  return (uint32_t)f2b(a) | ((uint32_t)f2b(b) << 16);
}

DEV float b2f_lo(uint32_t u) { return __uint_as_float(u << 16); }
DEV float b2f_hi(uint32_t u) { return __uint_as_float(u & 0xffff0000u); }

DEV void glds16(const void* g, void* l) {
  __builtin_amdgcn_global_load_lds(
      (const __attribute__((address_space(1))) void*)g,
      (__attribute__((address_space(3))) void*)l, 16, 0, 0);
}

DEV f32x4 mfma16(bf16x8 a, bf16x8 b, f32x4 c) {
  return __builtin_amdgcn_mfma_f32_16x16x32_bf16(a, b, c, 0, 0, 0);
}

#define BAR() __builtin_amdgcn_s_barrier()
#define WAIT_LGKM()                                      \
  {                                                      \
    asm volatile("s_waitcnt lgkmcnt(0)" ::: "memory");   \
    __builtin_amdgcn_sched_barrier(0);                   \
  }
#define WAIT_VM3() asm volatile("s_waitcnt vmcnt(3)" ::: "memory")
#define WAIT_VM4() asm volatile("s_waitcnt vmcnt(4)" ::: "memory")
#define WAIT_VM0() asm volatile("s_waitcnt vmcnt(0)" ::: "memory")

// ---------------- single fused fp32 -> bf16 conversion ----------------
__global__ __launch_bounds__(256) void cvt_all(
    const float* __restrict__ x, const float* __restrict__ Wq,
    const float* __restrict__ Wk, const float* __restrict__ Wv,
    const float* __restrict__ Wo, const float* __restrict__ bias,
    u16* __restrict__ xb, u16* __restrict__ wqkv, u16* __restrict__ wo,
    u16* __restrict__ biasb) {
  size_t i = ((size_t)blockIdx.x * 256 + threadIdx.x) * 4;
  const float* s;
  u16* d;
  size_t off;
  float scale = 1.0f;
  if (i < 8388608)        { s = x;  d = xb;             off = i; }
  else if (i < 9437184)   { s = Wq; d = wqkv;           off = i - 8388608; }
  else if (i < 10485760)  { s = Wk; d = wqkv + 1048576; off = i - 9437184; }
  else if (i < 11534336)  { s = Wv; d = wqkv + 2097152; off = i - 10485760; }
  else if (i < 12582912)  { s = Wo; d = wo;             off = i - 11534336; }
  else { s = bias; d = biasb; off = i - 12582912; scale = 1.44269504f; }
  float4 v = *(const float4*)(s + off);
  ushort4 o;
  o.x = f2b(v.x * scale); o.y = f2b(v.y * scale);
  o.z = f2b(v.z * scale); o.w = f2b(v.w * scale);
  *(ushort4*)(d + off) = o;
}

// ===== ring-3 GEMM core, 8-wave variant (BM=256,BN=128, 72 KiB) =====
// Round-7 proven: 65 us / MfmaUtil 32% on gemm_qkv. 512 threads = 8 waves,
// per-wave output 64x64. K in 32-wide halves g=0..31; ring of 3 regions.
// Phase g: read slot g%3 (8 ds_read_b128/wave), stage K-half g+2 into slot
// (g+2)%3 (3 glds16/wave), BAR, lgkm0, 16 MFMA, vmcnt(3), BAR.

DEV void stage_slot8(const u16* A, const u16* Bw, int m0, int n0, int col,
                     int wave, int srow, int scol, u16* slotA, u16* slotB) {
  const u16* srcA = A + (size_t)(m0 + wave * 32 + srow) * 1024 + col + scol;
  glds16(srcA, slotA + wave * 1024);
  glds16(srcA + (size_t)16 * 1024, slotA + wave * 1024 + 512);
  glds16(Bw + (size_t)(n0 + wave * 16 + srow) * 1024 + col + scol,
         slotB + wave * 512);
}

DEV void load_frags(const u16* Rbase, const u16* Cbase, int wr, int wc,
                    int c16, int swz, bf16x8 rf[4], bf16x8 cf[4]) {
#pragma unroll
  for (int i = 0; i < 4; ++i)
    rf[i] = *(const bf16x8*)&Rbase[(wr * 64 + i * 16 + c16) * 32 + swz];
#pragma unroll
  for (int i = 0; i < 4; ++i)
    cf[i] = *(const bf16x8*)&Cbase[(wc * 64 + i * 16 + c16) * 32 + swz];
}

DEV void mfma_all(bf16x8 rf[4], bf16x8 cf[4], f32x4 acc[4][4]) {
#pragma unroll
  for (int i = 0; i < 4; ++i)
#pragma unroll
    for (int j = 0; j < 4; ++j) acc[i][j] = mfma16(rf[i], cf[j], acc[i][j]);
}

DEV void gemm_core8(const u16* A, const u16* Bw, int m0, int n0, bool vblk,
                    int wave, int lane, u16 (*lsA)[8192], u16 (*lsB)[4096],
                    f32x4 acc[4][4]) {
  int q16 = lane >> 4, c16 = lane & 15;
  int wm = wave >> 1, wn = wave & 1;
  int wr = vblk ? wn : wm, wc = vblk ? wm : wn;
  int srow = lane >> 2;
  int scol = ((lane & 3) ^ ((lane >> 3) & 3)) * 8;  // staged XOR colgroup
  int swz = (q16 ^ ((c16 >> 1) & 3)) * 8;           // read-side colgroup

  stage_slot8(A, Bw, m0, n0, 0, wave, srow, scol, lsA[0], lsB[0]);
  stage_slot8(A, Bw, m0, n0, 32, wave, srow, scol, lsA[1], lsB[1]);
  WAIT_VM3();
  BAR();

#pragma unroll
  for (int g = 0; g < 32; ++g) {
    const int slot = g % 3;
    const u16* Rb = vblk ? &lsB[slot][0] : &lsA[slot][0];
    const u16* Cb = vblk ? &lsA[slot][0] : &lsB[slot][0];
    bf16x8 rf[4], cf[4];
    load_frags(Rb, Cb, wr, wc, c16, swz, rf, cf);
    if (g < 30)
      stage_slot8(A, Bw, m0, n0, (g + 2) * 32, wave, srow, scol,
                  lsA[(g + 2) % 3], lsB[(g + 2) % 3]);
    BAR();
    WAIT_LGKM();
    __builtin_amdgcn_s_setprio(1);
    mfma_all(rf, cf, acc);
    __builtin_amdgcn_s_setprio(0);
    if (g < 30) { WAIT_VM3(); } else if (g == 30) { WAIT_VM0(); }
    BAR();
  }
}

// ===== ring-3 GEMM core, 4-wave variant (BM=128,BN=128, 48 KiB) =====
// Round-8 proven on gemm_out (512 resident blocks, 2/CU, no lockstep tail).

DEV void stage_slot4(const u16* A, const u16* Bw, int m0, int n0, int col,
                     int wave, int srow, int scol, u16* slotA, u16* slotB) {
#pragma unroll
  for (int cc = 0; cc < 2; ++cc) {
    int unit = wave * 2 + cc;
    int r = unit * 16 + srow;
    glds16(A + (size_t)(m0 + r) * 1024 + col + scol, slotA + unit * 512);
    glds16(Bw + (size_t)(n0 + r) * 1024 + col + scol, slotB + unit * 512);
  }
}

DEV void gemm_core4(const u16* A, const u16* Bw, int m0, int n0,
                    int wave, int lane, u16 (*lsA)[4096], u16 (*lsB)[4096],
                    f32x4 acc[4][4]) {
  int q16 = lane >> 4, c16 = lane & 15;
  int wm = wave >> 1, wn = wave & 1;
  int srow = lane >> 2;
  int scol = ((lane & 3) ^ ((lane >> 3) & 3)) * 8;
  int swz = (q16 ^ ((c16 >> 1) & 3)) * 8;

  stage_slot4(A, Bw, m0, n0, 0, wave, srow, scol, lsA[0], lsB[0]);
  stage_slot4(A, Bw, m0, n0, 32, wave, srow, scol, lsA[1], lsB[1]);
  WAIT_VM4();
  BAR();

#pragma unroll
  for (int g = 0; g < 32; ++g) {
    const int slot = g % 3;
    bf16x8 rf[4], cf[4];
    load_frags(&lsA[slot][0], &lsB[slot][0], wm, wn, c16, swz, rf, cf);
    if (g < 30)
      stage_slot4(A, Bw, m0, n0, (g + 2) * 32, wave, srow, scol,
                  lsA[(g + 2) % 3], lsB[(g + 2) % 3]);
    BAR();
    WAIT_LGKM();
    __builtin_amdgcn_s_setprio(1);
    mfma_all(rf, cf, acc);
    __builtin_amdgcn_s_setprio(0);
    if (g < 30) { WAIT_VM4(); } else if (g == 30) { WAIT_VM0(); }
    BAR();
  }
}

// ---------------- fused QKV projection GEMM (8-wave core) ----------------
// A: (8192,1024) bf16 (x). Bw: (3072,1024) bf16 = [Wq;Wk;Wv] rows.
// Q,K -> (BH, T, 72) padded;  V -> (BH, 4, 64, 136) pre-tiled V^T.
__global__ __launch_bounds__(512, 4) void gemm_qkv(
    const u16* __restrict__ A, const u16* __restrict__ Bw,
    const float* __restrict__ bq, const float* __restrict__ bk,
    const float* __restrict__ bv,
    u16* __restrict__ qo, u16* __restrict__ ko, u16* __restrict__ vto) {
  __shared__ u16 lsA[3][8192];  // 48 KiB
  __shared__ u16 lsB[3][4096];  // 24 KiB
  int tid = threadIdx.x, wave = tid >> 6, lane = tid & 63;
  int q16 = lane >> 4, c16 = lane & 15;
  int m0 = blockIdx.y * 256, n0 = blockIdx.x * 128;
  int wm = wave >> 1, wn = wave & 1;
  const bool vblk = (n0 >= 2048);

  f32x4 acc[4][4];
#pragma unroll
  for (int i = 0; i < 4; ++i)
#pragma unroll
    for (int j = 0; j < 4; ++j) acc[i][j] = (f32x4)0.0f;

  gemm_core8(A, Bw, m0, n0, vblk, wave, lane, lsA, lsB, acc);

  if (!vblk) {
    // rows = m (t), cols = n (head dim)
#pragma unroll
    for (int mt = 0; mt < 4; ++mt) {
#pragma unroll
      for (int nt = 0; nt < 4; ++nt) {
        int n = n0 + wn * 64 + nt * 16 + c16;
        int which = n >> 10;
        int nl = n & 1023;
        int hh = nl >> 6, d = nl & 63;
        float bias = (which == 0 ? bq : bk)[nl];
        u16* dst = (which == 0 ? qo : ko);
#pragma unroll
        for (int r = 0; r < 4; ++r) {
          int m = m0 + wm * 64 + mt * 16 + q16 * 4 + r;
          int b = m >> 9, t = m & 511;
          size_t bh = (size_t)b * 16 + hh;
          dst[(bh * 512 + t) * 72 + d] = f2b(acc[mt][nt][r] + bias);
        }
      }
    }
  } else {
    // rows = n (head dim d), cols = m (t): D^T, coalesced over t
#pragma unroll
    for (int it = 0; it < 4; ++it) {
      int nbase = n0 + wn * 64 + it * 16 + q16 * 4;  // wr == wn
      float4 bvv = *(const float4*)(bv + (nbase & 1023));
#pragma unroll
      for (int jt = 0; jt < 4; ++jt) {
        int m = m0 + wm * 64 + jt * 16 + c16;  // wc == wm
        int b = m >> 9, t = m & 511;
        size_t bh4 = ((size_t)b * 16) * 4;
#pragma unroll
        for (int r = 0; r < 4; ++r) {
          int nl = (nbase + r) & 1023;
          int hh = nl >> 6, d = nl & 63;
          float bias = ((const float*)&bvv)[r];
          vto[((bh4 + (size_t)hh * 4 + (t >> 7)) * 64 + d) * 136 + (t & 127)] =
              f2b(acc[it][jt][r] + bias);
        }
      }
    }
  }
}

// ---------------- flash attention (S^T orientation) ----------------
// q,k: (BH, 512, 72) bf16 padded; vt: (BH, 4, 64, 136) bf16 pre-tiled V^T
// biasb: (H,512,512) bf16, pre-scaled by log2(e). out: (B,T,C) bf16.
// Work-balanced 640-block grid (4 tile-iters per block), 4 waves x 32 q-rows.
// LDS = 53248 B = 52.0 KiB -> 3 blocks/CU. 640 blocks fully resident.
__global__ __launch_bounds__(256, 3) void attn_kernel(
    const u16* __restrict__ qglob, const u16* __restrict__ kglob,
    const u16* __restrict__ vtglob, const u16* __restrict__ biasb,
    u16* __restrict__ og) {
  __shared__ u16 lsK[128 * 72];      // K tile (s,d) padded; also Q staging
  __shared__ u16 lsV[64 * 136];      // V^T tile (d,s) padded
  __shared__ u16 lsP[4 * 32 * 68];   // per-wave P half-tile (q, s-half)

  int tid = threadIdx.x, wave = tid >> 6, lane = tid & 63;
  int q16 = lane >> 4, c16 = lane & 15;
  u16* lsPw = lsP + wave * (32 * 68);

  int p = blockIdx.x;
  int bx, bh, bx2 = -1, bh2 = 0;
  if (p < 256)      { bx = 3; bh = p; }
  else if (p < 512) { bx = 2; bh = p - 256; bx2 = 0; bh2 = p - 256; }
  else              { int q = p - 512; bx = 1; bh = 2 * q; bx2 = 1; bh2 = 2 * q + 1; }

  for (;;) {
    int b = bh >> 4, h = bh & 15;
    int q0 = bx * 128;

    const u16* qbase = qglob + (size_t)bh * (512 * 72) + (size_t)q0 * 72;
    const u16* kbase = kglob + (size_t)bh * (512 * 72);
    const u16* vbase = vtglob + (size_t)bh * 4 * (64 * 136);

    // stage Q tile (contiguous 128x72 u16) into lsK
    for (int i = wave; i < 18; i += 4)
      glds16(qbase + (size_t)i * 512 + lane * 8, lsK + i * 512);
    __syncthreads();
    bf16x8 qf[2][2];
#pragma unroll
    for (int nt = 0; nt < 2; ++nt)
#pragma unroll
      for (int ks = 0; ks < 2; ++ks)
        qf[nt][ks] = *(const bf16x8*)&lsK[(wave * 32 + nt * 16 + c16) * 72 +
                                          ks * 32 + q16 * 8];

    f32x4 oacc[2][4];
#pragma unroll
    for (int i = 0; i < 2; ++i)
#pragma unroll
      for (int j = 0; j < 4; ++j) oacc[i][j] = (f32x4)0.0f;
    float mold[2] = {-INFINITY, -INFINITY};
    float lsum[2] = {0.0f, 0.0f};
    const float SCL = 0.18033688f;  // (1/sqrt(64)) * log2(e)

    for (int st = 0; st <= bx; ++st) {
      bool diag = (st == bx);
      __syncthreads();  // prior iter done with lsK/lsV/lsP
      const u16* kt = kbase + (size_t)st * (128 * 72);
      for (int i = wave; i < 18; i += 4)
        glds16(kt + (size_t)i * 512 + lane * 8, lsK + i * 512);
      const u16* vt = vbase + (size_t)st * (64 * 136);
      for (int i = wave; i < 17; i += 4)
        glds16(vt + (size_t)i * 512 + lane * 8, lsV + i * 512);

      // prefetch bias rows (bf16, pre-scaled); completes during staging drain
      uint2 ub[2][8];
#pragma unroll
      for (int nt = 0; nt < 2; ++nt) {
        int qgl = q0 + wave * 32 + nt * 16 + c16;
        const u16* bp =
            biasb + ((size_t)h * 512 + qgl) * 512 + st * 128 + q16 * 4;
#pragma unroll
        for (int mt = 0; mt < 8; ++mt) ub[nt][mt] = *(const uint2*)(bp + mt * 16);
      }
      __syncthreads();  // drains vmcnt (staging + bias prefetch)

      // S^T = K Q^T : rows s (8 m-tiles), cols q (2 n-tiles = wave's 32 rows)
      f32x4 sa[8][2];
#pragma unroll
      for (int mt = 0; mt < 8; ++mt) {
        sa[mt][0] = (f32x4)0.0f;
        sa[mt][1] = (f32x4)0.0f;
      }
      int mtmax = diag ? 2 * wave + 2 : 8;
#pragma unroll
      for (int mt = 0; mt < 8; ++mt) {
        if (mt < mtmax) {
#pragma unroll
          for (int ks = 0; ks < 2; ++ks) {
            bf16x8 kf =
                *(const bf16x8*)&lsK[(mt * 16 + c16) * 72 + ks * 32 + q16 * 8];
            sa[mt][0] = mfma16(kf, qf[0][ks], sa[mt][0]);
            sa[mt][1] = mfma16(kf, qf[1][ks], sa[mt][1]);
          }
        }
      }

      // online softmax: reduce over s = (mt, r) in-register + 2 shuffles
      float alpha[2];
#pragma unroll
      for (int nt = 0; nt < 2; ++nt) {
#pragma unroll
        for (int mt = 0; mt < 8; ++mt) {
          uint32_t lo = ub[nt][mt].x, hi = ub[nt][mt].y;
          f32x4 bv;
          bv[0] = b2f_lo(lo); bv[1] = b2f_hi(lo);
          bv[2] = b2f_lo(hi); bv[3] = b2f_hi(hi);
          sa[mt][nt] = sa[mt][nt] * SCL + bv;
        }
        if (diag) {
          // mask s > q  (s0 == q0 on diagonal tile)
#pragma unroll
          for (int mt = 0; mt < 8; ++mt) {
            int d0 = mt * 16 + q16 * 4 - wave * 32 - nt * 16 - c16;
#pragma unroll
            for (int r = 0; r < 4; ++r)
              if (d0 + r > 0) sa[mt][nt][r] = -INFINITY;
          }
        }
        f32x4 m4 = sa[0][nt];
#pragma unroll
        for (int mt = 1; mt < 8; ++mt) {
          f32x4 v = sa[mt][nt];
          m4[0] = fmaxf(m4[0], v[0]); m4[1] = fmaxf(m4[1], v[1]);
          m4[2] = fmaxf(m4[2], v[2]); m4[3] = fmaxf(m4[3], v[3]);
        }
        float mx = fmaxf(fmaxf(m4[0], m4[1]), fmaxf(m4[2], m4[3]));
        mx = fmaxf(mx, __shfl_xor(mx, 16));
        mx = fmaxf(mx, __shfl_xor(mx, 32));
        float mnew = fmaxf(mold[nt], mx);
        alpha[nt] = exp2f(mold[nt] - mnew);
        mold[nt] = mnew;
        f32x4 s4 = (f32x4)0.0f;
#pragma unroll
        for (int mt = 0; mt < 8; ++mt) {
          f32x4 pq;
          pq[0] = exp2f(sa[mt][nt][0] - mnew);
          pq[1] = exp2f(sa[mt][nt][1] - mnew);
          pq[2] = exp2f(sa[mt][nt][2] - mnew);
          pq[3] = exp2f(sa[mt][nt][3] - mnew);
          sa[mt][nt] = pq;
          s4 += pq;
        }
        float ss = (s4[0] + s4[1]) + (s4[2] + s4[3]);
        ss += __shfl_xor(ss, 16);
        ss += __shfl_xor(ss, 32);
        lsum[nt] = lsum[nt] * alpha[nt] + ss;
      }

      // rescale O by alpha (broadcast col-state -> row-state via shfl)
#pragma unroll
      for (int mo = 0; mo < 2; ++mo) {
        f32x4 av;
#pragma unroll
        for (int r = 0; r < 4; ++r) av[r] = __shfl(alpha[mo], q16 * 4 + r);
#pragma unroll
        for (int dt = 0; dt < 4; ++dt) oacc[mo][dt] *= av;
      }

      // O += P V, in two s-halves through per-wave LDS (C-layout -> A-layout)
      int G = diag ? wave + 1 : 4;  // valid 32-wide s-groups
#pragma unroll
      for (int hf = 0; hf < 2; ++hf) {
        if (hf * 2 < G) {
#pragma unroll
          for (int nt = 0; nt < 2; ++nt)
#pragma unroll
            for (int mt4 = 0; mt4 < 4; ++mt4) {
              f32x4 pv = sa[hf * 4 + mt4][nt];
              uint2 w;
              w.x = pk2(pv[0], pv[1]);
              w.y = pk2(pv[2], pv[3]);
              *(uint2*)&lsPw[(nt * 16 + c16) * 68 + mt4 * 16 + q16 * 4] = w;
            }
#pragma unroll
          for (int ksh = 0; ksh < 2; ++ksh) {
            if (hf * 2 + ksh < G) {
              bf16x8 pf0 =
                  *(const bf16x8*)&lsPw[c16 * 68 + ksh * 32 + q16 * 8];
              bf16x8 pf1 =
                  *(const bf16x8*)&lsPw[(16 + c16) * 68 + ksh * 32 + q16 * 8];
#pragma unroll
              for (int dt = 0; dt < 4; ++dt) {
                bf16x8 vf = *(const bf16x8*)&lsV[(dt * 16 + c16) * 136 +
                                                 hf * 64 + ksh * 32 + q16 * 8];
                oacc[0][dt] = mfma16(pf0, vf, oacc[0][dt]);
                oacc[1][dt] = mfma16(pf1, vf, oacc[1][dt]);
              }
            }
          }
        }
      }
    }

    // epilogue: O /= l, write (B,T,C) bf16
#pragma unroll
    for (int mo = 0; mo < 2; ++mo) {
      f32x4 lv;
#pragma unroll
      for (int r = 0; r < 4; ++r) lv[r] = __shfl(lsum[mo], q16 * 4 + r);
#pragma unroll
      for (int r = 0; r < 4; ++r) {
        int tg = q0 + wave * 32 + mo * 16 + q16 * 4 + r;
        float inv = 1.0f / lv[r];
#pragma unroll
        for (int dt = 0; dt < 4; ++dt)
          og[((size_t)b * 512 + tg) * 1024 + h * 64 + dt * 16 + c16] =
              f2b(oacc[mo][dt][r] * inv);
      }
    }

    if (bx2 < 0) break;
    __syncthreads();  // job 2 re-stages Q into lsK; job 1 may still read LDS
    bx = bx2; bh = bh2; bx2 = -1;
  }
}

// ------------- output projection GEMM (4-wave 128x128 ring-3 core) ---------
// Grid 8x64 = 512 blocks -> all resident (2/CU), uniform, no lockstep tail.
__global__ __launch_bounds__(256, 3) void gemm_out(
    const u16* __restrict__ A, const u16* __restrict__ W,
    const float* __restrict__ bo, float* __restrict__ out) {
  __shared__ u16 lsA[3][4096];  // 24 KiB
  __shared__ u16 lsB[3][4096];  // 24 KiB
  int tid = threadIdx.x, wave = tid >> 6, lane = tid & 63;
  int q16 = lane >> 4, c16 = lane & 15;
  int m0 = blockIdx.y * 128, n0 = blockIdx.x * 128;
  int wm = wave >> 1, wn = wave & 1;

  f32x4 acc[4][4];
#pragma unroll
  for (int i = 0; i < 4; ++i)
#pragma unroll
    for (int j = 0; j < 4; ++j) acc[i][j] = (f32x4)0.0f;

  gemm_core4(A, W, m0, n0, wave, lane, lsA, lsB, acc);

#pragma unroll
  for (int mt = 0; mt < 4; ++mt) {
#pragma unroll
    for (int nt = 0; nt < 4; ++nt) {
      int n = n0 + wn * 64 + nt * 16 + c16;
      float bias = bo[n];
#pragma unroll
      for (int r = 0; r < 4; ++r) {
        int m = m0 + wm * 64 + mt * 16 + q16 * 4 + r;
        out[(size_t)m * 1024 + n] = acc[mt][nt][r] + bias;
      }
    }
  }
}

extern "C" void kernel_launch(void* const* d_in, const int* in_sizes, int n_in,
                              void* d_out, int out_size, void* d_ws, size_t ws_size,
                              hipStream_t stream) {
  const float* x    = (const float*)d_in[0];
  const float* Wq   = (const float*)d_in[1];
  const float* bq   = (const float*)d_in[2];
  const float* Wk   = (const float*)d_in[3];
  const float* bk   = (const float*)d_in[4];
  const float* Wv   = (const float*)d_in[5];
  const float* bv   = (const float*)d_in[6];
  const float* Wo   = (const float*)d_in[7];
  const float* bo   = (const float*)d_in[8];
  const float* bias = (const float*)d_in[9];
  float* out = (float*)d_out;

  const size_t MB = 1u << 20;
  char* ws = (char*)d_ws;
  u16* xb    = (u16*)(ws);              // 16 MiB: x bf16 / reused as attn out
  u16* wqkv  = (u16*)(ws + 16 * MB);    // 6 MiB
  u16* wo    = (u16*)(ws + 22 * MB);    // 2 MiB
  u16* biasb = (u16*)(ws + 24 * MB);    // 8 MiB (bf16, pre-scaled by log2e)
  u16* qb    = (u16*)(ws + 32 * MB);    // 18 MiB (BH,512,72)
  u16* kb    = (u16*)(ws + 50 * MB);    // 18 MiB (BH,512,72)
  u16* vtb   = (u16*)(ws + 68 * MB);    // 17 MiB (BH,4,64,136)
  u16* ab    = xb;                      // attn output overlays xb

  cvt_all<<<16384, 256, 0, stream>>>(x, Wq, Wk, Wv, Wo, bias,
                                     xb, wqkv, wo, biasb);
  gemm_qkv<<<dim3(24, 32), 512, 0, stream>>>(xb, wqkv, bq, bk, bv, qb, kb, vtb);
  attn_kernel<<<dim3(640), 256, 0, stream>>>(qb, kb, vtb, biasb, ab);
  gemm_out<<<dim3(8, 64), 256, 0, stream>>>(ab, wo, bo, out);
}